// Round 1
// baseline (478.865 us; speedup 1.0000x reference)
//
#include <hip/hip_runtime.h>
#include <math.h>

// ---------------------------------------------------------------------------
// Problem constants: N=4, T=2048, D_MODEL=512, NHEAD=8, HEAD_DIM=64,
// window: key j valid for query i iff -127 <= j-i <= 128 and 0 <= j < T.
// Pipeline: qkv = x @ Wqkv^T ; rope(q,k) ; banded attention ; y = attn @ out_w^T + b
// ---------------------------------------------------------------------------

#define TILE 64
#define KT 32

// C[M,O] = A[M,K] * B[O,K]^T (+ bias[O] if bias != nullptr)
// Requires M,O multiples of 64, K multiple of 32. Row-major everything.
__global__ __launch_bounds__(256) void gemm_abt_kernel(
    const float* __restrict__ A, const float* __restrict__ B,
    const float* __restrict__ bias, float* __restrict__ C,
    int M, int O, int K)
{
    __shared__ float As[KT][TILE + 4];   // [k][m], stride 68 floats keeps 16B align
    __shared__ float Bs[KT][TILE + 4];   // [k][o]

    const int row0 = blockIdx.x * TILE;
    const int col0 = blockIdx.y * TILE;
    const int tid  = threadIdx.x;
    const int tm   = tid & 15;    // 16 m-positions x4
    const int tn   = tid >> 4;    // 16 n-positions x4
    const int lm   = tid & 63;    // staging row within tile
    const int lk   = (tid >> 6) * 4;  // staging k base per wave

    float acc[4][4] = {};

    const float* Arow = A + (size_t)(row0 + lm) * K;
    const float* Brow = B + (size_t)(col0 + lm) * K;

    for (int k0 = 0; k0 < K; k0 += KT) {
        #pragma unroll
        for (int kk = 0; kk < KT; kk += 16) {
            float4 a = *(const float4*)(Arow + k0 + lk + kk);
            As[lk + kk + 0][lm] = a.x;
            As[lk + kk + 1][lm] = a.y;
            As[lk + kk + 2][lm] = a.z;
            As[lk + kk + 3][lm] = a.w;
            float4 b = *(const float4*)(Brow + k0 + lk + kk);
            Bs[lk + kk + 0][lm] = b.x;
            Bs[lk + kk + 1][lm] = b.y;
            Bs[lk + kk + 2][lm] = b.z;
            Bs[lk + kk + 3][lm] = b.w;
        }
        __syncthreads();
        #pragma unroll
        for (int k = 0; k < KT; ++k) {
            float4 a = *(const float4*)&As[k][4 * tm];
            float4 b = *(const float4*)&Bs[k][4 * tn];
            acc[0][0] += a.x * b.x; acc[0][1] += a.x * b.y;
            acc[0][2] += a.x * b.z; acc[0][3] += a.x * b.w;
            acc[1][0] += a.y * b.x; acc[1][1] += a.y * b.y;
            acc[1][2] += a.y * b.z; acc[1][3] += a.y * b.w;
            acc[2][0] += a.z * b.x; acc[2][1] += a.z * b.y;
            acc[2][2] += a.z * b.z; acc[2][3] += a.z * b.w;
            acc[3][0] += a.w * b.x; acc[3][1] += a.w * b.y;
            acc[3][2] += a.w * b.z; acc[3][3] += a.w * b.w;
        }
        __syncthreads();
    }

    float b0 = 0.f, b1 = 0.f, b2 = 0.f, b3 = 0.f;
    if (bias) {
        b0 = bias[col0 + 4 * tn + 0];
        b1 = bias[col0 + 4 * tn + 1];
        b2 = bias[col0 + 4 * tn + 2];
        b3 = bias[col0 + 4 * tn + 3];
    }
    #pragma unroll
    for (int i = 0; i < 4; ++i) {
        const int row = row0 + 4 * tm + i;
        float4 o;
        o.x = acc[i][0] + b0;
        o.y = acc[i][1] + b1;
        o.z = acc[i][2] + b2;
        o.w = acc[i][3] + b3;
        *(float4*)&C[(size_t)row * O + col0 + 4 * tn] = o;
    }
}

// In-place RoPE on the q and k slices of qkv[(n*T+t)][1536].
// One thread per element of q and k; partner (d^32) fetched via shuffle.
__global__ __launch_bounds__(256) void rope_kernel(float* __restrict__ qkv)
{
    const unsigned tid = threadIdx.x;
    const size_t e = (size_t)blockIdx.x * 256 + tid;   // [0, 8192*1024)
    const int nt    = (int)(e >> 10);        // n*2048 + t
    const int r     = (int)(e & 1023);
    const int which = r >> 9;                // 0 = q, 1 = k
    const int w     = r & 511;               // h*64 + d
    const int d     = w & 63;
    const int t     = nt & 2047;

    const size_t idx = (size_t)nt * 1536 + (size_t)which * 512 + w;
    float u = qkv[idx];
    float partner = __shfl_xor(u, 32, 64);   // element with d^32 (same wave)

    const int i = d & 31;
    // inv_freq[i] = 10000^(-i/32) ; ln(10000)/32 = 0.28782313662425574
    float inv_freq = expf(-(float)i * 0.28782313662425574f);
    float ang = (float)t * inv_freq;
    float s, c;
    sincosf(ang, &s, &c);
    float rot = (d < 32) ? -partner : partner;
    qkv[idx] = u * c + rot * s;
}

// Banded attention. Block = 256 threads handles (n, h, 64-query tile).
// Thread: q = tid>>2 (query row), g = tid&3 (16-dim output slice, 16-key score slice).
__global__ __launch_bounds__(256) void attn_kernel(
    const float* __restrict__ qkv, float* __restrict__ attnout)
{
    __shared__ float kv[64][68];   // K tile, then reused as V tile
    __shared__ float S[64][68];    // probabilities

    const int qt = blockIdx.x;     // 0..31
    const int h  = blockIdx.y;     // 0..7
    const int n  = blockIdx.z;     // 0..3
    const int t0 = qt * 64;
    const int tid = threadIdx.x;
    const int q   = tid >> 2;      // 0..63
    const int g   = tid & 3;       // 0..3
    const int d0  = g * 16;
    const int tq  = t0 + q;        // global query position

    // Full q row (64 floats) in registers (4 threads per row duplicate the load).
    float4 qreg[16];
    {
        const float* qp = qkv + (size_t)(n * 2048 + tq) * 1536 + h * 64;
        #pragma unroll
        for (int i = 0; i < 16; ++i) qreg[i] = *(const float4*)(qp + 4 * i);
    }

    float m_r = -1e30f;
    float l_r = 0.f;
    float acc[16];
    #pragma unroll
    for (int i = 0; i < 16; ++i) acc[i] = 0.f;

    for (int dt = -2; dt <= 2; ++dt) {
        const int kt = qt + dt;
        if (kt < 0 || kt > 31) continue;
        const int s0 = kt * 64;

        // Stage K tile: row q, 16 floats at d0.
        {
            const float* kp = qkv + (size_t)(n * 2048 + s0 + q) * 1536 + 512 + h * 64 + d0;
            #pragma unroll
            for (int i = 0; i < 4; ++i)
                *(float4*)&kv[q][d0 + 4 * i] = *(const float4*)(kp + 4 * i);
        }
        __syncthreads();

        // Scores for 16 keys j = 4*jj + g (g-interleaved to spread LDS banks).
        float sc[16];
        #pragma unroll 4
        for (int jj = 0; jj < 16; ++jj) {
            const int j = (jj << 2) | g;
            float dot = 0.f;
            #pragma unroll
            for (int dd = 0; dd < 16; ++dd) {
                float4 k4 = *(const float4*)&kv[j][4 * dd];
                dot += qreg[dd].x * k4.x + qreg[dd].y * k4.y
                     + qreg[dd].z * k4.z + qreg[dd].w * k4.w;
            }
            const int diff = (s0 + j) - tq;
            sc[jj] = (diff >= -127 && diff <= 128) ? dot * 0.125f : -1e30f;
        }

        float tmax = sc[0];
        #pragma unroll
        for (int jj = 1; jj < 16; ++jj) tmax = fmaxf(tmax, sc[jj]);
        tmax = fmaxf(tmax, __shfl_xor(tmax, 1, 64));
        tmax = fmaxf(tmax, __shfl_xor(tmax, 2, 64));

        const float m_new = fmaxf(m_r, tmax);
        const float alpha = expf(m_r - m_new);   // exp(-huge)->0 wipes masked-tile pollution
        float psum = 0.f;
        #pragma unroll
        for (int jj = 0; jj < 16; ++jj) {
            const int j = (jj << 2) | g;
            float p = expf(sc[jj] - m_new);
            psum += p;
            S[q][j] = p;
        }
        psum += __shfl_xor(psum, 1, 64);
        psum += __shfl_xor(psum, 2, 64);
        l_r = l_r * alpha + psum;
        m_r = m_new;
        #pragma unroll
        for (int i = 0; i < 16; ++i) acc[i] *= alpha;

        __syncthreads();   // S complete; all K-tile reads done

        // Stage V tile over the K tile.
        {
            const float* vp = qkv + (size_t)(n * 2048 + s0 + q) * 1536 + 1024 + h * 64 + d0;
            #pragma unroll
            for (int i = 0; i < 4; ++i)
                *(float4*)&kv[q][d0 + 4 * i] = *(const float4*)(vp + 4 * i);
        }
        __syncthreads();

        // acc[d0..d0+15] += sum_j p[q][j] * V[j][d0..]
        #pragma unroll 8
        for (int j = 0; j < 64; ++j) {
            const float pj = S[q][j];
            float4 v0 = *(const float4*)&kv[j][d0 + 0];
            float4 v1 = *(const float4*)&kv[j][d0 + 4];
            float4 v2 = *(const float4*)&kv[j][d0 + 8];
            float4 v3 = *(const float4*)&kv[j][d0 + 12];
            acc[0]  += pj * v0.x; acc[1]  += pj * v0.y;
            acc[2]  += pj * v0.z; acc[3]  += pj * v0.w;
            acc[4]  += pj * v1.x; acc[5]  += pj * v1.y;
            acc[6]  += pj * v1.z; acc[7]  += pj * v1.w;
            acc[8]  += pj * v2.x; acc[9]  += pj * v2.y;
            acc[10] += pj * v2.z; acc[11] += pj * v2.w;
            acc[12] += pj * v3.x; acc[13] += pj * v3.y;
            acc[14] += pj * v3.z; acc[15] += pj * v3.w;
        }
        __syncthreads();   // kv/S reads done before next tile overwrites
    }

    const float inv_l = 1.0f / l_r;
    float* op = attnout + (size_t)(n * 2048 + tq) * 512 + h * 64 + d0;
    #pragma unroll
    for (int i = 0; i < 4; ++i) {
        float4 o;
        o.x = acc[4 * i + 0] * inv_l;
        o.y = acc[4 * i + 1] * inv_l;
        o.z = acc[4 * i + 2] * inv_l;
        o.w = acc[4 * i + 3] * inv_l;
        *(float4*)(op + 4 * i) = o;
    }
}

extern "C" void kernel_launch(void* const* d_in, const int* in_sizes, int n_in,
                              void* d_out, int out_size, void* d_ws, size_t ws_size,
                              hipStream_t stream)
{
    (void)in_sizes; (void)n_in; (void)out_size; (void)ws_size;

    const float* x     = (const float*)d_in[0];   // (4,2048,512)
    const float* Wqkv  = (const float*)d_in[1];   // (1536,512)
    const float* out_w = (const float*)d_in[2];   // (512,512)
    const float* out_b = (const float*)d_in[3];   // (512,)
    float* out = (float*)d_out;                   // (4,2048,512)

    float* qkv  = (float*)d_ws;                        // 8192*1536 floats (48 MB)
    float* attn = qkv + (size_t)8192 * 1536;           // 8192*512 floats (16 MB)

    // 1) qkv = x @ Wqkv^T
    gemm_abt_kernel<<<dim3(128, 24), 256, 0, stream>>>(x, Wqkv, nullptr, qkv,
                                                       8192, 1536, 512);
    // 2) RoPE in place on q,k
    rope_kernel<<<32768, 256, 0, stream>>>(qkv);
    // 3) banded attention -> attn[(n*T+t)][h*64+d]
    attn_kernel<<<dim3(32, 8, 4), 256, 0, stream>>>(qkv, attn);
    // 4) out = attn @ out_w^T + out_b
    gemm_abt_kernel<<<dim3(128, 8), 256, 0, stream>>>(attn, out_w, out_b, out,
                                                      8192, 512, 512);
}

// Round 2
// 273.345 us; speedup vs baseline: 1.7519x; 1.7519x over previous
//
#include <hip/hip_runtime.h>
#include <math.h>

// ---------------------------------------------------------------------------
// N=4, T=2048, D_MODEL=512, NHEAD=8, HEAD_DIM=64, window -127..+128.
// Pipeline: cvt(x,Wqkv,out_w)->bf16 ; qkv_bf16 = x@Wqkv^T (MFMA) ; rope(bf16) ;
//           banded attention (fp32 math, bf16 io) ; out = attn@out_w^T + b (MFMA)
// ---------------------------------------------------------------------------

typedef __attribute__((ext_vector_type(8))) __bf16 bf16x8;
typedef __attribute__((ext_vector_type(4))) float f32x4;

__device__ __forceinline__ unsigned short f2bf(float f) {
    unsigned int u = __float_as_uint(f);
    u += 0x7fffu + ((u >> 16) & 1u);
    return (unsigned short)(u >> 16);
}
__device__ __forceinline__ unsigned int packbf2(float a, float b) {
    unsigned int ua = __float_as_uint(a); ua += 0x7fffu + ((ua >> 16) & 1u);
    unsigned int ub = __float_as_uint(b); ub += 0x7fffu + ((ub >> 16) & 1u);
    return (ua >> 16) | (ub & 0xffff0000u);
}
__device__ __forceinline__ float bf2f(unsigned short s) {
    return __uint_as_float(((unsigned int)s) << 16);
}
__device__ __forceinline__ void unpack8(const unsigned short* p, float* o) {
    uint4 u = *(const uint4*)p;
    o[0] = __uint_as_float(u.x << 16); o[1] = __uint_as_float(u.x & 0xffff0000u);
    o[2] = __uint_as_float(u.y << 16); o[3] = __uint_as_float(u.y & 0xffff0000u);
    o[4] = __uint_as_float(u.z << 16); o[5] = __uint_as_float(u.z & 0xffff0000u);
    o[6] = __uint_as_float(u.w << 16); o[7] = __uint_as_float(u.w & 0xffff0000u);
}

__device__ __forceinline__ void async16(void* lds, const void* g) {
    __builtin_amdgcn_global_load_lds(
        (const __attribute__((address_space(1))) void*)g,
        (__attribute__((address_space(3))) void*)lds,
        16, 0, 0);
}

// fp32 -> bf16, 4 elements/thread
__global__ __launch_bounds__(256) void cvt_f32_bf16(
    const float* __restrict__ in, unsigned short* __restrict__ out, int n4)
{
    const int i = blockIdx.x * 256 + threadIdx.x;
    if (i < n4) {
        float4 v = *(const float4*)(in + 4 * (size_t)i);
        uint2 o;
        o.x = packbf2(v.x, v.y);
        o.y = packbf2(v.z, v.w);
        *(uint2*)(out + 4 * (size_t)i) = o;
    }
}

// C[M,O] = A[M,K](bf16) * B[O,K](bf16)^T (+bias). Output fp32 or bf16.
// BM=BN=128, BK=32. Block=256 (4 waves, each 64x64 via 4x4 MFMA 16x16x32).
__global__ __launch_bounds__(256) void gemm_bt_mfma(
    const unsigned short* __restrict__ A, const unsigned short* __restrict__ B,
    const float* __restrict__ bias, void* __restrict__ Cout,
    int M, int O, int K, int write_bf16)
{
    __shared__ unsigned short As[128 * 32];
    __shared__ unsigned short Bs[128 * 32];

    const int tid  = threadIdx.x;
    const int wave = tid >> 6;
    const int lane = tid & 63;
    const int row0 = blockIdx.x * 128;
    const int col0 = blockIdx.y * 128;
    const int wr   = (wave >> 1) * 64;
    const int wc   = (wave & 1) * 64;

    f32x4 acc[4][4] = {};

    const int r_a  = tid >> 2;         // staging row (set 0); set 1 adds 64
    const int cblk = (tid & 3) * 8;    // k-element offset of 8-elem chunk
    const int qk   = (lane >> 4) * 8;  // frag k offset
    const int lrow = lane & 15;

    for (int k0 = 0; k0 < K; k0 += 32) {
        async16(&As[(size_t)tid * 8],         A + (size_t)(row0 + r_a) * K + k0 + cblk);
        async16(&As[(size_t)(tid + 256) * 8], A + (size_t)(row0 + 64 + r_a) * K + k0 + cblk);
        async16(&Bs[(size_t)tid * 8],         B + (size_t)(col0 + r_a) * K + k0 + cblk);
        async16(&Bs[(size_t)(tid + 256) * 8], B + (size_t)(col0 + 64 + r_a) * K + k0 + cblk);
        __syncthreads();

        bf16x8 af[4], bfr[4];
        #pragma unroll
        for (int mt = 0; mt < 4; ++mt)
            af[mt] = *(const bf16x8*)&As[(wr + mt * 16 + lrow) * 32 + qk];
        #pragma unroll
        for (int nt = 0; nt < 4; ++nt)
            bfr[nt] = *(const bf16x8*)&Bs[(wc + nt * 16 + lrow) * 32 + qk];

        #pragma unroll
        for (int mt = 0; mt < 4; ++mt)
            #pragma unroll
            for (int nt = 0; nt < 4; ++nt)
                acc[mt][nt] = __builtin_amdgcn_mfma_f32_16x16x32_bf16(
                    af[mt], bfr[nt], acc[mt][nt], 0, 0, 0);
        __syncthreads();
    }

    const int qrow = (lane >> 4) * 4;
    #pragma unroll
    for (int nt = 0; nt < 4; ++nt) {
        const int col = col0 + wc + nt * 16 + lrow;
        const float bv = bias ? bias[col] : 0.f;
        #pragma unroll
        for (int mt = 0; mt < 4; ++mt) {
            const int rowb = row0 + wr + mt * 16 + qrow;
            if (write_bf16) {
                unsigned short* C = (unsigned short*)Cout;
                #pragma unroll
                for (int r = 0; r < 4; ++r)
                    C[(size_t)(rowb + r) * O + col] = f2bf(acc[mt][nt][r] + bv);
            } else {
                float* C = (float*)Cout;
                #pragma unroll
                for (int r = 0; r < 4; ++r)
                    C[(size_t)(rowb + r) * O + col] = acc[mt][nt][r] + bv;
            }
        }
    }
}

// In-place RoPE on bf16 q,k slices of qkv[(n*T+t)][1536].
__global__ __launch_bounds__(256) void rope_bf16_kernel(unsigned short* __restrict__ qkv)
{
    const unsigned tid = threadIdx.x;
    const size_t e = (size_t)blockIdx.x * 256 + tid;   // [0, 8192*1024)
    const int nt    = (int)(e >> 10);
    const int r     = (int)(e & 1023);
    const int which = r >> 9;
    const int w     = r & 511;
    const int d     = w & 63;
    const int t     = nt & 2047;

    const size_t idx = (size_t)nt * 1536 + (size_t)which * 512 + w;
    float u = bf2f(qkv[idx]);
    float partner = __shfl_xor(u, 32, 64);

    const int i = d & 31;
    float inv_freq = expf(-(float)i * 0.28782313662425574f);  // 10000^(-i/32)
    float ang = (float)t * inv_freq;
    float s, c;
    sincosf(ang, &s, &c);
    float rot = (d < 32) ? -partner : partner;
    qkv[idx] = f2bf(u * c + rot * s);
}

// Banded attention, fp32 math, bf16 in/out.
// Block=256: (n, h, 64-query tile). Thread: q=tid>>2, g=tid&3 (16-dim slice).
__global__ __launch_bounds__(256) void attn_kernel(
    const unsigned short* __restrict__ qkv, unsigned short* __restrict__ attnout)
{
    __shared__ float kv[64][68];
    __shared__ float S[64][68];

    const int qt = blockIdx.x;
    const int h  = blockIdx.y;
    const int n  = blockIdx.z;
    const int t0 = qt * 64;
    const int tid = threadIdx.x;
    const int q   = tid >> 2;
    const int g   = tid & 3;
    const int d0  = g * 16;
    const int tq  = t0 + q;

    float qreg[64];
    {
        const unsigned short* qp = qkv + (size_t)(n * 2048 + tq) * 1536 + h * 64;
        #pragma unroll
        for (int i = 0; i < 8; ++i) unpack8(qp + 8 * i, qreg + 8 * i);
    }

    float m_r = -1e30f;
    float l_r = 0.f;
    float acc[16];
    #pragma unroll
    for (int i = 0; i < 16; ++i) acc[i] = 0.f;

    for (int dt = -2; dt <= 2; ++dt) {
        const int kt = qt + dt;
        if (kt < 0 || kt > 31) continue;
        const int s0 = kt * 64;

        {   // stage K tile: row q, 16 bf16 at d0
            const unsigned short* kp =
                qkv + (size_t)(n * 2048 + s0 + q) * 1536 + 512 + h * 64 + d0;
            float f[16];
            unpack8(kp, f); unpack8(kp + 8, f + 8);
            #pragma unroll
            for (int i = 0; i < 4; ++i)
                *(float4*)&kv[q][d0 + 4 * i] =
                    make_float4(f[4*i], f[4*i+1], f[4*i+2], f[4*i+3]);
        }
        __syncthreads();

        float sc[16];
        #pragma unroll 4
        for (int jj = 0; jj < 16; ++jj) {
            const int j = (jj << 2) | g;
            float dot = 0.f;
            #pragma unroll
            for (int dd = 0; dd < 16; ++dd) {
                float4 k4 = *(const float4*)&kv[j][4 * dd];
                dot += qreg[4*dd+0] * k4.x + qreg[4*dd+1] * k4.y
                     + qreg[4*dd+2] * k4.z + qreg[4*dd+3] * k4.w;
            }
            const int diff = (s0 + j) - tq;
            sc[jj] = (diff >= -127 && diff <= 128) ? dot * 0.125f : -1e30f;
        }

        float tmax = sc[0];
        #pragma unroll
        for (int jj = 1; jj < 16; ++jj) tmax = fmaxf(tmax, sc[jj]);
        tmax = fmaxf(tmax, __shfl_xor(tmax, 1, 64));
        tmax = fmaxf(tmax, __shfl_xor(tmax, 2, 64));

        const float m_new = fmaxf(m_r, tmax);
        const float alpha = expf(m_r - m_new);
        float psum = 0.f;
        #pragma unroll
        for (int jj = 0; jj < 16; ++jj) {
            const int j = (jj << 2) | g;
            float p = expf(sc[jj] - m_new);
            psum += p;
            S[q][j] = p;
        }
        psum += __shfl_xor(psum, 1, 64);
        psum += __shfl_xor(psum, 2, 64);
        l_r = l_r * alpha + psum;
        m_r = m_new;
        #pragma unroll
        for (int i = 0; i < 16; ++i) acc[i] *= alpha;

        __syncthreads();

        {   // stage V tile over K tile
            const unsigned short* vp =
                qkv + (size_t)(n * 2048 + s0 + q) * 1536 + 1024 + h * 64 + d0;
            float f[16];
            unpack8(vp, f); unpack8(vp + 8, f + 8);
            #pragma unroll
            for (int i = 0; i < 4; ++i)
                *(float4*)&kv[q][d0 + 4 * i] =
                    make_float4(f[4*i], f[4*i+1], f[4*i+2], f[4*i+3]);
        }
        __syncthreads();

        #pragma unroll 8
        for (int j = 0; j < 64; ++j) {
            const float pj = S[q][j];
            float4 v0 = *(const float4*)&kv[j][d0 + 0];
            float4 v1 = *(const float4*)&kv[j][d0 + 4];
            float4 v2 = *(const float4*)&kv[j][d0 + 8];
            float4 v3 = *(const float4*)&kv[j][d0 + 12];
            acc[0]  += pj * v0.x; acc[1]  += pj * v0.y;
            acc[2]  += pj * v0.z; acc[3]  += pj * v0.w;
            acc[4]  += pj * v1.x; acc[5]  += pj * v1.y;
            acc[6]  += pj * v1.z; acc[7]  += pj * v1.w;
            acc[8]  += pj * v2.x; acc[9]  += pj * v2.y;
            acc[10] += pj * v2.z; acc[11] += pj * v2.w;
            acc[12] += pj * v3.x; acc[13] += pj * v3.y;
            acc[14] += pj * v3.z; acc[15] += pj * v3.w;
        }
        __syncthreads();
    }

    const float inv_l = 1.0f / l_r;
    unsigned short* op = attnout + (size_t)(n * 2048 + tq) * 512 + h * 64 + d0;
    uint4 u0, u1;
    u0.x = packbf2(acc[0] * inv_l,  acc[1] * inv_l);
    u0.y = packbf2(acc[2] * inv_l,  acc[3] * inv_l);
    u0.z = packbf2(acc[4] * inv_l,  acc[5] * inv_l);
    u0.w = packbf2(acc[6] * inv_l,  acc[7] * inv_l);
    u1.x = packbf2(acc[8] * inv_l,  acc[9] * inv_l);
    u1.y = packbf2(acc[10] * inv_l, acc[11] * inv_l);
    u1.z = packbf2(acc[12] * inv_l, acc[13] * inv_l);
    u1.w = packbf2(acc[14] * inv_l, acc[15] * inv_l);
    *(uint4*)op = u0;
    *(uint4*)(op + 8) = u1;
}

extern "C" void kernel_launch(void* const* d_in, const int* in_sizes, int n_in,
                              void* d_out, int out_size, void* d_ws, size_t ws_size,
                              hipStream_t stream)
{
    (void)in_sizes; (void)n_in; (void)out_size; (void)ws_size;

    const float* x     = (const float*)d_in[0];   // (4,2048,512)
    const float* Wqkv  = (const float*)d_in[1];   // (1536,512)
    const float* out_w = (const float*)d_in[2];   // (512,512)
    const float* out_b = (const float*)d_in[3];   // (512,)
    float* out = (float*)d_out;                   // (4,2048,512)

    unsigned short* qkvb  = (unsigned short*)d_ws;          // 8192*1536 bf16 (24MB)
    unsigned short* attnb = qkvb + (size_t)8192 * 1536;     // 8192*512  bf16 (8MB)
    unsigned short* xb    = attnb + (size_t)8192 * 512;     // 8192*512  bf16 (8MB)
    unsigned short* wqkvb = xb + (size_t)8192 * 512;        // 1536*512  bf16
    unsigned short* outwb = wqkvb + (size_t)1536 * 512;     // 512*512   bf16

    // 0) fp32 -> bf16 conversions
    cvt_f32_bf16<<<4096, 256, 0, stream>>>(x, xb, 8192 * 512 / 4);
    cvt_f32_bf16<<<768, 256, 0, stream>>>(Wqkv, wqkvb, 1536 * 512 / 4);
    cvt_f32_bf16<<<256, 256, 0, stream>>>(out_w, outwb, 512 * 512 / 4);

    // 1) qkv = x @ Wqkv^T  (bf16 out)
    gemm_bt_mfma<<<dim3(64, 12), 256, 0, stream>>>(xb, wqkvb, nullptr, qkvb,
                                                   8192, 1536, 512, 1);
    // 2) RoPE in place on q,k
    rope_bf16_kernel<<<32768, 256, 0, stream>>>(qkvb);
    // 3) banded attention -> attnb bf16
    attn_kernel<<<dim3(32, 8, 4), 256, 0, stream>>>(qkvb, attnb);
    // 4) out = attn @ out_w^T + out_b  (fp32 out)
    gemm_bt_mfma<<<dim3(64, 4), 256, 0, stream>>>(attnb, outwb, out_b, out,
                                                  8192, 512, 512, 0);
}

// Round 4
// 161.203 us; speedup vs baseline: 2.9706x; 1.6957x over previous
//
#include <hip/hip_runtime.h>
#include <math.h>

// ---------------------------------------------------------------------------
// N=4, T=2048, D_MODEL=512, NHEAD=8, HEAD_DIM=64, window -127..+128.
// Pipeline: cvt(x,Wqkv,out_w)->bf16 ; qkv = x@Wqkv^T (MFMA) ; rope(bf16) ;
//           flash attention (MFMA QK^T & PV, online softmax) ; out GEMM (MFMA)
// ---------------------------------------------------------------------------

typedef __attribute__((ext_vector_type(8))) __bf16 bf16x8;
typedef __attribute__((ext_vector_type(4))) float f32x4;

__device__ __forceinline__ unsigned short f2bf(float f) {
    unsigned int u = __float_as_uint(f);
    u += 0x7fffu + ((u >> 16) & 1u);
    return (unsigned short)(u >> 16);
}
__device__ __forceinline__ unsigned int packbf2(float a, float b) {
    unsigned int ua = __float_as_uint(a); ua += 0x7fffu + ((ua >> 16) & 1u);
    unsigned int ub = __float_as_uint(b); ub += 0x7fffu + ((ub >> 16) & 1u);
    return (ua >> 16) | (ub & 0xffff0000u);
}
__device__ __forceinline__ float bf2f(unsigned short s) {
    return __uint_as_float(((unsigned int)s) << 16);
}
__device__ __forceinline__ bf16x8 as_bf16x8(uint4 u) {
    union { uint4 u4; bf16x8 v; } c; c.u4 = u; return c.v;
}

__device__ __forceinline__ void async16(void* lds, const void* g) {
    __builtin_amdgcn_global_load_lds(
        (const __attribute__((address_space(1))) void*)g,
        (__attribute__((address_space(3))) void*)lds,
        16, 0, 0);
}

// fp32 -> bf16, 4 elements/thread
__global__ __launch_bounds__(256) void cvt_f32_bf16(
    const float* __restrict__ in, unsigned short* __restrict__ out, int n4)
{
    const int i = blockIdx.x * 256 + threadIdx.x;
    if (i < n4) {
        float4 v = *(const float4*)(in + 4 * (size_t)i);
        uint2 o;
        o.x = packbf2(v.x, v.y);
        o.y = packbf2(v.z, v.w);
        *(uint2*)(out + 4 * (size_t)i) = o;
    }
}

// C[M,O] = A[M,K](bf16) * B[O,K](bf16)^T (+bias). Output fp32 or bf16.
__global__ __launch_bounds__(256) void gemm_bt_mfma(
    const unsigned short* __restrict__ A, const unsigned short* __restrict__ B,
    const float* __restrict__ bias, void* __restrict__ Cout,
    int M, int O, int K, int write_bf16)
{
    __shared__ __align__(16) unsigned short As[128 * 32];
    __shared__ __align__(16) unsigned short Bs[128 * 32];

    const int tid  = threadIdx.x;
    const int wave = tid >> 6;
    const int lane = tid & 63;
    const int row0 = blockIdx.x * 128;
    const int col0 = blockIdx.y * 128;
    const int wr   = (wave >> 1) * 64;
    const int wc   = (wave & 1) * 64;

    f32x4 acc[4][4] = {};

    const int r_a  = tid >> 2;
    const int cblk = (tid & 3) * 8;
    const int qk   = (lane >> 4) * 8;
    const int lrow = lane & 15;

    for (int k0 = 0; k0 < K; k0 += 32) {
        async16(&As[(size_t)tid * 8],         A + (size_t)(row0 + r_a) * K + k0 + cblk);
        async16(&As[(size_t)(tid + 256) * 8], A + (size_t)(row0 + 64 + r_a) * K + k0 + cblk);
        async16(&Bs[(size_t)tid * 8],         B + (size_t)(col0 + r_a) * K + k0 + cblk);
        async16(&Bs[(size_t)(tid + 256) * 8], B + (size_t)(col0 + 64 + r_a) * K + k0 + cblk);
        __syncthreads();

        bf16x8 af[4], bfr[4];
        #pragma unroll
        for (int mt = 0; mt < 4; ++mt)
            af[mt] = as_bf16x8(*(const uint4*)&As[(wr + mt * 16 + lrow) * 32 + qk]);
        #pragma unroll
        for (int nt = 0; nt < 4; ++nt)
            bfr[nt] = as_bf16x8(*(const uint4*)&Bs[(wc + nt * 16 + lrow) * 32 + qk]);

        #pragma unroll
        for (int mt = 0; mt < 4; ++mt)
            #pragma unroll
            for (int nt = 0; nt < 4; ++nt)
                acc[mt][nt] = __builtin_amdgcn_mfma_f32_16x16x32_bf16(
                    af[mt], bfr[nt], acc[mt][nt], 0, 0, 0);
        __syncthreads();
    }

    const int qrow = (lane >> 4) * 4;
    #pragma unroll
    for (int nt = 0; nt < 4; ++nt) {
        const int col = col0 + wc + nt * 16 + lrow;
        const float bv = bias ? bias[col] : 0.f;
        #pragma unroll
        for (int mt = 0; mt < 4; ++mt) {
            const int rowb = row0 + wr + mt * 16 + qrow;
            if (write_bf16) {
                unsigned short* C = (unsigned short*)Cout;
                #pragma unroll
                for (int r = 0; r < 4; ++r)
                    C[(size_t)(rowb + r) * O + col] = f2bf(acc[mt][nt][r] + bv);
            } else {
                float* C = (float*)Cout;
                #pragma unroll
                for (int r = 0; r < 4; ++r)
                    C[(size_t)(rowb + r) * O + col] = acc[mt][nt][r] + bv;
            }
        }
    }
}

// In-place RoPE on bf16 q,k slices of qkv[(n*T+t)][1536].
__global__ __launch_bounds__(256) void rope_bf16_kernel(unsigned short* __restrict__ qkv)
{
    const unsigned tid = threadIdx.x;
    const size_t e = (size_t)blockIdx.x * 256 + tid;
    const int nt    = (int)(e >> 10);
    const int r     = (int)(e & 1023);
    const int which = r >> 9;
    const int w     = r & 511;
    const int d     = w & 63;
    const int t     = nt & 2047;

    const size_t idx = (size_t)nt * 1536 + (size_t)which * 512 + w;
    float u = bf2f(qkv[idx]);
    float partner = __shfl_xor(u, 32, 64);

    const int i = d & 31;
    float inv_freq = expf(-(float)i * 0.28782313662425574f);  // 10000^(-i/32)
    float ang = (float)t * inv_freq;
    float s, c;
    sincosf(ang, &s, &c);
    float rot = (d < 32) ? -partner : partner;
    qkv[idx] = f2bf(u * c + rot * s);
}

// Flash attention with MFMA. Block=256 (4 waves) handles (qt, h, n):
// 64 query rows; wave w owns queries t0+16w..+15. 5 key tiles of 64.
// LDS rows padded to 72 bf16 (144 B): 16B-aligned rows, 2-way conflicts (free).
__global__ __launch_bounds__(256) void attn_mfma_kernel(
    const unsigned short* __restrict__ qkv, unsigned short* __restrict__ attnout)
{
    __shared__ __align__(16) unsigned short Kt[64 * 72];      // [key][dim]
    __shared__ __align__(16) unsigned short Vt[64 * 72];      // [dim][key]
    __shared__ __align__(16) unsigned short Ps[4][16 * 72];   // per-wave P [query][key]

    const int qt = blockIdx.x;   // 0..31
    const int h  = blockIdx.y;   // 0..7
    const int n  = blockIdx.z;   // 0..3
    const int t0 = qt * 64;
    const int tid  = threadIdx.x;
    const int wave = tid >> 6;
    const int lane = tid & 63;
    const int l15  = lane & 15;
    const int lg   = lane >> 4;          // 0..3

    const size_t base = (size_t)n * 2048 * 1536 + (size_t)h * 64;

    // Q A-fragments: A[m = l15][k = lg*8 + j (+32 for kstep 1)]
    bf16x8 qfrag[2];
    {
        const unsigned short* qp = qkv + base + (size_t)(t0 + wave * 16 + l15) * 1536;
        qfrag[0] = as_bf16x8(*(const uint4*)(qp + lg * 8));
        qfrag[1] = as_bf16x8(*(const uint4*)(qp + 32 + lg * 8));
    }

    // staging: thread handles key = tid>>2, dims sd0..sd0+15
    const int skey = tid >> 2;
    const int sd0  = (tid & 3) * 16;

    float m_r[4], l_r[4];
    #pragma unroll
    for (int r = 0; r < 4; ++r) { m_r[r] = -1e30f; l_r[r] = 0.f; }
    f32x4 acc_o[4] = {};   // [nt]: dim = nt*16+l15, query row = lg*4+r

    for (int dt = -2; dt <= 2; ++dt) {
        const int kt = qt + dt;
        if (kt < 0 || kt > 31) continue;
        const int s0 = kt * 64;

        // ---- stage K tile (copy) and V tile (transpose via register extract) ----
        {
            const unsigned short* kp = qkv + base + 512 + (size_t)(s0 + skey) * 1536 + sd0;
            uint4 k0 = *(const uint4*)kp;
            uint4 k1 = *(const uint4*)(kp + 8);
            *(uint4*)&Kt[skey * 72 + sd0]     = k0;
            *(uint4*)&Kt[skey * 72 + sd0 + 8] = k1;

            const unsigned short* vp = qkv + base + 1024 + (size_t)(s0 + skey) * 1536 + sd0;
            uint4 a = *(const uint4*)vp;
            uint4 b = *(const uint4*)(vp + 8);
            Vt[(sd0 +  0) * 72 + skey] = (unsigned short)(a.x & 0xffffu);
            Vt[(sd0 +  1) * 72 + skey] = (unsigned short)(a.x >> 16);
            Vt[(sd0 +  2) * 72 + skey] = (unsigned short)(a.y & 0xffffu);
            Vt[(sd0 +  3) * 72 + skey] = (unsigned short)(a.y >> 16);
            Vt[(sd0 +  4) * 72 + skey] = (unsigned short)(a.z & 0xffffu);
            Vt[(sd0 +  5) * 72 + skey] = (unsigned short)(a.z >> 16);
            Vt[(sd0 +  6) * 72 + skey] = (unsigned short)(a.w & 0xffffu);
            Vt[(sd0 +  7) * 72 + skey] = (unsigned short)(a.w >> 16);
            Vt[(sd0 +  8) * 72 + skey] = (unsigned short)(b.x & 0xffffu);
            Vt[(sd0 +  9) * 72 + skey] = (unsigned short)(b.x >> 16);
            Vt[(sd0 + 10) * 72 + skey] = (unsigned short)(b.y & 0xffffu);
            Vt[(sd0 + 11) * 72 + skey] = (unsigned short)(b.y >> 16);
            Vt[(sd0 + 12) * 72 + skey] = (unsigned short)(b.z & 0xffffu);
            Vt[(sd0 + 13) * 72 + skey] = (unsigned short)(b.z >> 16);
            Vt[(sd0 + 14) * 72 + skey] = (unsigned short)(b.w & 0xffffu);
            Vt[(sd0 + 15) * 72 + skey] = (unsigned short)(b.w >> 16);
        }
        __syncthreads();

        // ---- S = Q K^T ----
        f32x4 acc_s[4] = {};   // [nt]: key col = nt*16+l15, query row = lg*4+r
        #pragma unroll
        for (int kstep = 0; kstep < 2; ++kstep) {
            #pragma unroll
            for (int nt = 0; nt < 4; ++nt) {
                bf16x8 kf = as_bf16x8(
                    *(const uint4*)&Kt[(nt * 16 + l15) * 72 + kstep * 32 + lg * 8]);
                acc_s[nt] = __builtin_amdgcn_mfma_f32_16x16x32_bf16(
                    qfrag[kstep], kf, acc_s[nt], 0, 0, 0);
            }
        }

        // ---- mask + scale + online softmax (row = query = lg*4+r) ----
        float sc[4][4];   // [nt][r]
        #pragma unroll
        for (int nt = 0; nt < 4; ++nt) {
            const int key_off = dt * 64 + nt * 16 + l15;        // key - t0
            #pragma unroll
            for (int r = 0; r < 4; ++r) {
                const int diff = key_off - (wave * 16 + lg * 4 + r);  // key - query
                const bool ok = (diff >= -127) && (diff <= 128);
                sc[nt][r] = ok ? acc_s[nt][r] * 0.125f : -1e30f;
            }
        }
        #pragma unroll
        for (int r = 0; r < 4; ++r) {
            float tm = fmaxf(fmaxf(sc[0][r], sc[1][r]), fmaxf(sc[2][r], sc[3][r]));
            tm = fmaxf(tm, __shfl_xor(tm, 1, 64));
            tm = fmaxf(tm, __shfl_xor(tm, 2, 64));
            tm = fmaxf(tm, __shfl_xor(tm, 4, 64));
            tm = fmaxf(tm, __shfl_xor(tm, 8, 64));
            const float m_new = fmaxf(m_r[r], tm);
            const float alpha = expf(m_r[r] - m_new);
            float psum = 0.f;
            #pragma unroll
            for (int nt = 0; nt < 4; ++nt) {
                float p = expf(sc[nt][r] - m_new);
                sc[nt][r] = p;
                psum += p;
            }
            psum += __shfl_xor(psum, 1, 64);
            psum += __shfl_xor(psum, 2, 64);
            psum += __shfl_xor(psum, 4, 64);
            psum += __shfl_xor(psum, 8, 64);
            l_r[r] = l_r[r] * alpha + psum;
            m_r[r] = m_new;
            #pragma unroll
            for (int nt = 0; nt < 4; ++nt) acc_o[nt][r] *= alpha;
        }

        // ---- P -> LDS (C layout) -> A-frag layout ----
        #pragma unroll
        for (int nt = 0; nt < 4; ++nt)
            #pragma unroll
            for (int r = 0; r < 4; ++r)
                Ps[wave][(lg * 4 + r) * 72 + nt * 16 + l15] = f2bf(sc[nt][r]);

        __syncthreads();   // ensure P visible (and ordering) before re-read

        bf16x8 pfrag[2];
        pfrag[0] = as_bf16x8(*(const uint4*)&Ps[wave][l15 * 72 + lg * 8]);
        pfrag[1] = as_bf16x8(*(const uint4*)&Ps[wave][l15 * 72 + 32 + lg * 8]);

        // ---- O += P V (B = V^T from Vt) ----
        #pragma unroll
        for (int kstep = 0; kstep < 2; ++kstep) {
            #pragma unroll
            for (int nt = 0; nt < 4; ++nt) {
                bf16x8 vf = as_bf16x8(
                    *(const uint4*)&Vt[(nt * 16 + l15) * 72 + kstep * 32 + lg * 8]);
                acc_o[nt] = __builtin_amdgcn_mfma_f32_16x16x32_bf16(
                    pfrag[kstep], vf, acc_o[nt], 0, 0, 0);
            }
        }
        __syncthreads();   // Kt/Vt/Ps reads done before next tile's staging
    }

    float inv_l[4];
    #pragma unroll
    for (int r = 0; r < 4; ++r) inv_l[r] = 1.0f / l_r[r];

    #pragma unroll
    for (int r = 0; r < 4; ++r) {
        const int tq = t0 + wave * 16 + lg * 4 + r;
        unsigned short* op = attnout + (size_t)(n * 2048 + tq) * 512 + h * 64;
        #pragma unroll
        for (int nt = 0; nt < 4; ++nt)
            op[nt * 16 + l15] = f2bf(acc_o[nt][r] * inv_l[r]);
    }
}

extern "C" void kernel_launch(void* const* d_in, const int* in_sizes, int n_in,
                              void* d_out, int out_size, void* d_ws, size_t ws_size,
                              hipStream_t stream)
{
    (void)in_sizes; (void)n_in; (void)out_size; (void)ws_size;

    const float* x     = (const float*)d_in[0];
    const float* Wqkv  = (const float*)d_in[1];
    const float* out_w = (const float*)d_in[2];
    const float* out_b = (const float*)d_in[3];
    float* out = (float*)d_out;

    unsigned short* qkvb  = (unsigned short*)d_ws;          // 8192*1536 bf16
    unsigned short* attnb = qkvb + (size_t)8192 * 1536;     // 8192*512  bf16
    unsigned short* xb    = attnb + (size_t)8192 * 512;     // 8192*512  bf16
    unsigned short* wqkvb = xb + (size_t)8192 * 512;        // 1536*512  bf16
    unsigned short* outwb = wqkvb + (size_t)1536 * 512;     // 512*512   bf16

    cvt_f32_bf16<<<4096, 256, 0, stream>>>(x, xb, 8192 * 512 / 4);
    cvt_f32_bf16<<<768, 256, 0, stream>>>(Wqkv, wqkvb, 1536 * 512 / 4);
    cvt_f32_bf16<<<256, 256, 0, stream>>>(out_w, outwb, 512 * 512 / 4);

    gemm_bt_mfma<<<dim3(64, 12), 256, 0, stream>>>(xb, wqkvb, nullptr, qkvb,
                                                   8192, 1536, 512, 1);
    rope_bf16_kernel<<<32768, 256, 0, stream>>>(qkvb);
    attn_mfma_kernel<<<dim3(32, 8, 4), 256, 0, stream>>>(qkvb, attnb);
    gemm_bt_mfma<<<dim3(64, 4), 256, 0, stream>>>(attnb, outwb, out_b, out,
                                                  8192, 512, 512, 0);
}

// Round 5
// 154.667 us; speedup vs baseline: 3.0961x; 1.0423x over previous
//
#include <hip/hip_runtime.h>
#include <math.h>

// ---------------------------------------------------------------------------
// N=4, T=2048, D_MODEL=512, NHEAD=8, HEAD_DIM=64, window -127..+128.
// Pipeline: cvt_all(x,Wqkv,out_w)->bf16 ; qkv = x@Wqkv^T + fused RoPE + q-scale
//           (MFMA) ; flash attention (MFMA) ; out = attn@out_w^T + b (MFMA)
// ---------------------------------------------------------------------------

typedef __attribute__((ext_vector_type(8))) __bf16 bf16x8;
typedef __attribute__((ext_vector_type(4))) float f32x4;

__device__ __forceinline__ unsigned short f2bf(float f) {
    unsigned int u = __float_as_uint(f);
    u += 0x7fffu + ((u >> 16) & 1u);
    return (unsigned short)(u >> 16);
}
__device__ __forceinline__ unsigned int packbf2(float a, float b) {
    unsigned int ua = __float_as_uint(a); ua += 0x7fffu + ((ua >> 16) & 1u);
    unsigned int ub = __float_as_uint(b); ub += 0x7fffu + ((ub >> 16) & 1u);
    return (ua >> 16) | (ub & 0xffff0000u);
}
__device__ __forceinline__ bf16x8 as_bf16x8(uint4 u) {
    union { uint4 u4; bf16x8 v; } c; c.u4 = u; return c.v;
}

__device__ __forceinline__ void async16(void* lds, const void* g) {
    __builtin_amdgcn_global_load_lds(
        (const __attribute__((address_space(1))) void*)g,
        (__attribute__((address_space(3))) void*)lds,
        16, 0, 0);
}

// One kernel converts all three fp32 inputs to bf16 (4 elems/thread).
__global__ __launch_bounds__(256) void cvt_all(
    const float* __restrict__ x, const float* __restrict__ w1,
    const float* __restrict__ w2,
    unsigned short* __restrict__ xb, unsigned short* __restrict__ w1b,
    unsigned short* __restrict__ w2b)
{
    const int n_x  = 8192 * 512 / 4;
    const int n_w1 = 1536 * 512 / 4;
    const int n_w2 = 512 * 512 / 4;
    int i = blockIdx.x * 256 + threadIdx.x;
    const float* in; unsigned short* out; int j;
    if (i < n_x)                  { in = x;  out = xb;  j = i; }
    else if (i < n_x + n_w1)      { in = w1; out = w1b; j = i - n_x; }
    else if (i < n_x + n_w1 + n_w2) { in = w2; out = w2b; j = i - n_x - n_w1; }
    else return;
    float4 v = *(const float4*)(in + 4 * (size_t)j);
    uint2 o;
    o.x = packbf2(v.x, v.y);
    o.y = packbf2(v.z, v.w);
    *(uint2*)(out + 4 * (size_t)j) = o;
}

// C[M,O] = A[M,K](bf16) * B[O,K](bf16)^T (+bias). Output fp32 or bf16.
// do_rope: O==1536 qkv layout; apply RoPE to cols<1024 (pairing col^32 which
// lives in the same thread at nt^2) and fold 1/8 scale into q (cols<512).
__global__ __launch_bounds__(256) void gemm_bt_mfma(
    const unsigned short* __restrict__ A, const unsigned short* __restrict__ B,
    const float* __restrict__ bias, void* __restrict__ Cout,
    int M, int O, int K, int write_bf16, int do_rope)
{
    __shared__ __align__(16) unsigned short As[128 * 32];
    __shared__ __align__(16) unsigned short Bs[128 * 32];

    const int tid  = threadIdx.x;
    const int wave = tid >> 6;
    const int lane = tid & 63;
    const int row0 = blockIdx.x * 128;
    const int col0 = blockIdx.y * 128;
    const int wr   = (wave >> 1) * 64;
    const int wc   = (wave & 1) * 64;

    f32x4 acc[4][4] = {};

    const int r_a  = tid >> 2;
    const int cblk = (tid & 3) * 8;
    const int qk   = (lane >> 4) * 8;
    const int lrow = lane & 15;

    for (int k0 = 0; k0 < K; k0 += 32) {
        async16(&As[(size_t)tid * 8],         A + (size_t)(row0 + r_a) * K + k0 + cblk);
        async16(&As[(size_t)(tid + 256) * 8], A + (size_t)(row0 + 64 + r_a) * K + k0 + cblk);
        async16(&Bs[(size_t)tid * 8],         B + (size_t)(col0 + r_a) * K + k0 + cblk);
        async16(&Bs[(size_t)(tid + 256) * 8], B + (size_t)(col0 + 64 + r_a) * K + k0 + cblk);
        __syncthreads();

        bf16x8 af[4], bfr[4];
        #pragma unroll
        for (int mt = 0; mt < 4; ++mt)
            af[mt] = as_bf16x8(*(const uint4*)&As[(wr + mt * 16 + lrow) * 32 + qk]);
        #pragma unroll
        for (int nt = 0; nt < 4; ++nt)
            bfr[nt] = as_bf16x8(*(const uint4*)&Bs[(wc + nt * 16 + lrow) * 32 + qk]);

        #pragma unroll
        for (int mt = 0; mt < 4; ++mt)
            #pragma unroll
            for (int nt = 0; nt < 4; ++nt)
                acc[mt][nt] = __builtin_amdgcn_mfma_f32_16x16x32_bf16(
                    af[mt], bfr[nt], acc[mt][nt], 0, 0, 0);
        __syncthreads();
    }

    const int qrow = (lane >> 4) * 4;

    // Fused RoPE on q,k accumulator columns. col = col0+wc+nt*16+lrow,
    // d = col&63 = nt*16+lrow (wc bit is 64). i = d&31: nt&1 selects 16+lrow.
    // Partner col^32 = accumulator nt^2 (same thread).
    if (do_rope && col0 < 1024) {
        const float cfreq = 0.28782313662425574f;   // ln(10000)/32
        const float invf0 = expf(-(float)lrow * cfreq);
        const float invf1 = expf(-(float)(16 + lrow) * cfreq);
        #pragma unroll
        for (int mt = 0; mt < 4; ++mt) {
            #pragma unroll
            for (int r = 0; r < 4; ++r) {
                const int t = (row0 + wr + mt * 16 + qrow + r) & 2047;
                #pragma unroll
                for (int p = 0; p < 2; ++p) {
                    float ang = (float)t * (p ? invf1 : invf0);
                    float s, c;
                    sincosf(ang, &s, &c);
                    float a = acc[mt][p][r];       // d = p*16+lrow  (< 32)
                    float b = acc[mt][p + 2][r];   // d = 32 + p*16+lrow
                    acc[mt][p][r]     = a * c - b * s;
                    acc[mt][p + 2][r] = b * c + a * s;
                }
            }
        }
        if (col0 < 512) {   // q block: fold softmax scale 1/sqrt(64)
            #pragma unroll
            for (int mt = 0; mt < 4; ++mt)
                #pragma unroll
                for (int nt = 0; nt < 4; ++nt)
                    #pragma unroll
                    for (int r = 0; r < 4; ++r)
                        acc[mt][nt][r] *= 0.125f;
        }
    }

    #pragma unroll
    for (int nt = 0; nt < 4; ++nt) {
        const int col = col0 + wc + nt * 16 + lrow;
        const float bv = bias ? bias[col] : 0.f;
        #pragma unroll
        for (int mt = 0; mt < 4; ++mt) {
            const int rowb = row0 + wr + mt * 16 + qrow;
            if (write_bf16) {
                unsigned short* C = (unsigned short*)Cout;
                #pragma unroll
                for (int r = 0; r < 4; ++r)
                    C[(size_t)(rowb + r) * O + col] = f2bf(acc[mt][nt][r] + bv);
            } else {
                float* C = (float*)Cout;
                #pragma unroll
                for (int r = 0; r < 4; ++r)
                    C[(size_t)(rowb + r) * O + col] = acc[mt][nt][r] + bv;
            }
        }
    }
}

// Flash attention with MFMA. Block=256 (4 waves) handles (qt, h, n).
// q is pre-scaled by 1/8 in the QKV GEMM epilogue.
__global__ __launch_bounds__(256) void attn_mfma_kernel(
    const unsigned short* __restrict__ qkv, unsigned short* __restrict__ attnout)
{
    __shared__ __align__(16) unsigned short Kt[64 * 72];      // [key][dim]
    __shared__ __align__(16) unsigned short Vt[64 * 72];      // [dim][key]
    __shared__ __align__(16) unsigned short Ps[4][16 * 72];   // per-wave P

    const int qt = blockIdx.x;
    const int h  = blockIdx.y;
    const int n  = blockIdx.z;
    const int t0 = qt * 64;
    const int tid  = threadIdx.x;
    const int wave = tid >> 6;
    const int lane = tid & 63;
    const int l15  = lane & 15;
    const int lg   = lane >> 4;

    const size_t base = (size_t)n * 2048 * 1536 + (size_t)h * 64;

    bf16x8 qfrag[2];
    {
        const unsigned short* qp = qkv + base + (size_t)(t0 + wave * 16 + l15) * 1536;
        qfrag[0] = as_bf16x8(*(const uint4*)(qp + lg * 8));
        qfrag[1] = as_bf16x8(*(const uint4*)(qp + 32 + lg * 8));
    }

    const int skey = tid >> 2;
    const int sd0  = (tid & 3) * 16;

    float m_r[4], l_r[4];
    #pragma unroll
    for (int r = 0; r < 4; ++r) { m_r[r] = -1e30f; l_r[r] = 0.f; }
    f32x4 acc_o[4] = {};

    for (int dt = -2; dt <= 2; ++dt) {
        const int kt = qt + dt;
        if (kt < 0 || kt > 31) continue;
        const int s0 = kt * 64;

        {
            const unsigned short* kp = qkv + base + 512 + (size_t)(s0 + skey) * 1536 + sd0;
            uint4 k0 = *(const uint4*)kp;
            uint4 k1 = *(const uint4*)(kp + 8);
            *(uint4*)&Kt[skey * 72 + sd0]     = k0;
            *(uint4*)&Kt[skey * 72 + sd0 + 8] = k1;

            const unsigned short* vp = qkv + base + 1024 + (size_t)(s0 + skey) * 1536 + sd0;
            uint4 a = *(const uint4*)vp;
            uint4 b = *(const uint4*)(vp + 8);
            Vt[(sd0 +  0) * 72 + skey] = (unsigned short)(a.x & 0xffffu);
            Vt[(sd0 +  1) * 72 + skey] = (unsigned short)(a.x >> 16);
            Vt[(sd0 +  2) * 72 + skey] = (unsigned short)(a.y & 0xffffu);
            Vt[(sd0 +  3) * 72 + skey] = (unsigned short)(a.y >> 16);
            Vt[(sd0 +  4) * 72 + skey] = (unsigned short)(a.z & 0xffffu);
            Vt[(sd0 +  5) * 72 + skey] = (unsigned short)(a.z >> 16);
            Vt[(sd0 +  6) * 72 + skey] = (unsigned short)(a.w & 0xffffu);
            Vt[(sd0 +  7) * 72 + skey] = (unsigned short)(a.w >> 16);
            Vt[(sd0 +  8) * 72 + skey] = (unsigned short)(b.x & 0xffffu);
            Vt[(sd0 +  9) * 72 + skey] = (unsigned short)(b.x >> 16);
            Vt[(sd0 + 10) * 72 + skey] = (unsigned short)(b.y & 0xffffu);
            Vt[(sd0 + 11) * 72 + skey] = (unsigned short)(b.y >> 16);
            Vt[(sd0 + 12) * 72 + skey] = (unsigned short)(b.z & 0xffffu);
            Vt[(sd0 + 13) * 72 + skey] = (unsigned short)(b.z >> 16);
            Vt[(sd0 + 14) * 72 + skey] = (unsigned short)(b.w & 0xffffu);
            Vt[(sd0 + 15) * 72 + skey] = (unsigned short)(b.w >> 16);
        }
        __syncthreads();

        f32x4 acc_s[4] = {};
        #pragma unroll
        for (int kstep = 0; kstep < 2; ++kstep) {
            #pragma unroll
            for (int nt = 0; nt < 4; ++nt) {
                bf16x8 kf = as_bf16x8(
                    *(const uint4*)&Kt[(nt * 16 + l15) * 72 + kstep * 32 + lg * 8]);
                acc_s[nt] = __builtin_amdgcn_mfma_f32_16x16x32_bf16(
                    qfrag[kstep], kf, acc_s[nt], 0, 0, 0);
            }
        }

        float sc[4][4];
        #pragma unroll
        for (int nt = 0; nt < 4; ++nt) {
            const int key_off = dt * 64 + nt * 16 + l15;
            #pragma unroll
            for (int r = 0; r < 4; ++r) {
                const int diff = key_off - (wave * 16 + lg * 4 + r);
                const bool ok = (diff >= -127) && (diff <= 128);
                sc[nt][r] = ok ? acc_s[nt][r] : -1e30f;   // scale pre-folded into q
            }
        }
        #pragma unroll
        for (int r = 0; r < 4; ++r) {
            float tm = fmaxf(fmaxf(sc[0][r], sc[1][r]), fmaxf(sc[2][r], sc[3][r]));
            tm = fmaxf(tm, __shfl_xor(tm, 1, 64));
            tm = fmaxf(tm, __shfl_xor(tm, 2, 64));
            tm = fmaxf(tm, __shfl_xor(tm, 4, 64));
            tm = fmaxf(tm, __shfl_xor(tm, 8, 64));
            const float m_new = fmaxf(m_r[r], tm);
            const float alpha = expf(m_r[r] - m_new);
            float psum = 0.f;
            #pragma unroll
            for (int nt = 0; nt < 4; ++nt) {
                float p = expf(sc[nt][r] - m_new);
                sc[nt][r] = p;
                psum += p;
            }
            psum += __shfl_xor(psum, 1, 64);
            psum += __shfl_xor(psum, 2, 64);
            psum += __shfl_xor(psum, 4, 64);
            psum += __shfl_xor(psum, 8, 64);
            l_r[r] = l_r[r] * alpha + psum;
            m_r[r] = m_new;
            #pragma unroll
            for (int nt = 0; nt < 4; ++nt) acc_o[nt][r] *= alpha;
        }

        #pragma unroll
        for (int nt = 0; nt < 4; ++nt)
            #pragma unroll
            for (int r = 0; r < 4; ++r)
                Ps[wave][(lg * 4 + r) * 72 + nt * 16 + l15] = f2bf(sc[nt][r]);

        __syncthreads();

        bf16x8 pfrag[2];
        pfrag[0] = as_bf16x8(*(const uint4*)&Ps[wave][l15 * 72 + lg * 8]);
        pfrag[1] = as_bf16x8(*(const uint4*)&Ps[wave][l15 * 72 + 32 + lg * 8]);

        #pragma unroll
        for (int kstep = 0; kstep < 2; ++kstep) {
            #pragma unroll
            for (int nt = 0; nt < 4; ++nt) {
                bf16x8 vf = as_bf16x8(
                    *(const uint4*)&Vt[(nt * 16 + l15) * 72 + kstep * 32 + lg * 8]);
                acc_o[nt] = __builtin_amdgcn_mfma_f32_16x16x32_bf16(
                    pfrag[kstep], vf, acc_o[nt], 0, 0, 0);
            }
        }
        __syncthreads();
    }

    float inv_l[4];
    #pragma unroll
    for (int r = 0; r < 4; ++r) inv_l[r] = 1.0f / l_r[r];

    #pragma unroll
    for (int r = 0; r < 4; ++r) {
        const int tq = t0 + wave * 16 + lg * 4 + r;
        unsigned short* op = attnout + (size_t)(n * 2048 + tq) * 512 + h * 64;
        #pragma unroll
        for (int nt = 0; nt < 4; ++nt)
            op[nt * 16 + l15] = f2bf(acc_o[nt][r] * inv_l[r]);
    }
}

extern "C" void kernel_launch(void* const* d_in, const int* in_sizes, int n_in,
                              void* d_out, int out_size, void* d_ws, size_t ws_size,
                              hipStream_t stream)
{
    (void)in_sizes; (void)n_in; (void)out_size; (void)ws_size;

    const float* x     = (const float*)d_in[0];
    const float* Wqkv  = (const float*)d_in[1];
    const float* out_w = (const float*)d_in[2];
    const float* out_b = (const float*)d_in[3];
    float* out = (float*)d_out;

    unsigned short* qkvb  = (unsigned short*)d_ws;          // 8192*1536 bf16
    unsigned short* attnb = qkvb + (size_t)8192 * 1536;     // 8192*512  bf16
    unsigned short* xb    = attnb + (size_t)8192 * 512;     // 8192*512  bf16
    unsigned short* wqkvb = xb + (size_t)8192 * 512;        // 1536*512  bf16
    unsigned short* outwb = wqkvb + (size_t)1536 * 512;     // 512*512   bf16

    // 0) all fp32->bf16 conversions in one launch
    cvt_all<<<5120, 256, 0, stream>>>(x, Wqkv, out_w, xb, wqkvb, outwb);

    // 1) qkv = x @ Wqkv^T with fused RoPE + q-scale (bf16 out)
    gemm_bt_mfma<<<dim3(64, 12), 256, 0, stream>>>(xb, wqkvb, nullptr, qkvb,
                                                   8192, 1536, 512, 1, 1);
    // 2) flash attention -> attnb bf16
    attn_mfma_kernel<<<dim3(32, 8, 4), 256, 0, stream>>>(qkvb, attnb);
    // 3) out = attn @ out_w^T + out_b (fp32 out)
    gemm_bt_mfma<<<dim3(64, 4), 256, 0, stream>>>(attnb, outwb, out_b, out,
                                                  8192, 512, 512, 0, 0);
}